// Round 2
// baseline (760.581 us; speedup 1.0000x reference)
//
#include <hip/hip_runtime.h>
#include <hip/hip_bf16.h>
#include <math.h>

#define B_DIM 65536
#define N_DIM 1024
#define BM 64
#define BN 512
#define BK 32
#define NKT (N_DIM / BK)
#define THREADS 512
#define DT_C 0.01f
#define NS_SCALE 0.01f   // NOISE_STD * sqrt(DT) = 0.1 * 0.1

typedef __attribute__((ext_vector_type(8))) short bf16x8;
typedef __attribute__((ext_vector_type(4))) float f32x4;

__device__ __forceinline__ unsigned short f2bf(float f) {
    union { float f; unsigned int u; } a;
    a.f = f;
    unsigned int r = a.u + 0x7fffu + ((a.u >> 16) & 1u);
    return (unsigned short)(r >> 16);
}

__device__ __forceinline__ void gload_lds16(const void* g, void* l) {
    __builtin_amdgcn_global_load_lds(
        (const __attribute__((address_space(1))) void*)g,
        (__attribute__((address_space(3))) void*)l, 16, 0, 0);
}

// K (fp32, row-major N x N) -> bf16
__global__ void k_convK(const float* __restrict__ K, unsigned short* __restrict__ Kbf) {
    int i = blockIdx.x * blockDim.x + threadIdx.x;
    float4 v = reinterpret_cast<const float4*>(K)[i];
    ushort4 o;
    o.x = f2bf(v.x); o.y = f2bf(v.y); o.z = f2bf(v.z); o.w = f2bf(v.w);
    reinterpret_cast<ushort4*>(Kbf)[i] = o;
}

// Fused: Ks = sin(theta) @ K^T, Kc = cos(theta) @ K^T (bf16 MFMA),
// out = theta + (omega + cos*Ks - sin*Kc)*DT + noise*NS_SCALE
__global__ __launch_bounds__(THREADS, 2)
void k_fused(const float* __restrict__ theta,
             const float* __restrict__ noise,
             const float* __restrict__ omega,
             const unsigned short* __restrict__ Kbf,
             float* __restrict__ out) {
    // LDS: k-chunk-major 16B granules: [buf][s/c][q][row][8]  and  [buf][q][col][8]
    __shared__ unsigned short sA[2][2][4][BM][8];     // 16 KB
    __shared__ unsigned short sB[2][4][BN][8];        // 64 KB

    const int tid  = threadIdx.x;
    const int lane = tid & 63;
    const int w    = tid >> 6;       // wave 0..7
    const int wm   = w >> 2;         // 0..1  (32 rows each)
    const int wn   = w & 3;          // 0..3  (128 cols each)

    // XCD-aware swizzle: group both column-tiles of a row-panel on one XCD
    const int nwg     = gridDim.x;         // 2048, divisible by 8
    const int cpx     = nwg >> 3;
    const int logical = (blockIdx.x & 7) * cpx + (blockIdx.x >> 3);
    const int mt      = logical >> 1;      // 0..1023
    const int nt      = logical & 1;       // 0..1
    const int row0    = mt * BM;
    const int col0    = nt * BN;

    // staging decomposition for A: thread -> (q, r, h)
    const int q = tid >> 7;          // k-chunk 0..3
    const int r = (tid >> 1) & 63;   // row 0..63
    const int h = tid & 1;           // half 0..1 (4 elems)

    f32x4 accS[2][8], accC[2][8];
#pragma unroll
    for (int mi = 0; mi < 2; ++mi)
#pragma unroll
        for (int ni = 0; ni < 8; ++ni) {
            accS[mi][ni] = (f32x4){0.f, 0.f, 0.f, 0.f};
            accC[mi][ni] = (f32x4){0.f, 0.f, 0.f, 0.f};
        }

    // ---- phase pieces ----
    auto a_load = [&](int kt) -> float4 {
        const float* gp = theta + (size_t)(row0 + r) * N_DIM + kt * BK + q * 8 + h * 4;
        return *reinterpret_cast<const float4*>(gp);
    };
    auto b_issue = [&](int buf, int kt) {
#pragma unroll
        for (int it = 0; it < 4; ++it) {
            const unsigned short* src =
                Kbf + (size_t)(col0 + tid) * N_DIM + kt * BK + it * 8;
            unsigned short* dst = &sB[buf][it][w << 6][0];
            gload_lds16(src, dst);
        }
    };
    auto a_finish = [&](int buf, float4 v) {
        ushort4 sv, cv;
        float s0, c0, s1, c1, s2, c2, s3, c3;
        __sincosf(v.x, &s0, &c0);
        __sincosf(v.y, &s1, &c1);
        __sincosf(v.z, &s2, &c2);
        __sincosf(v.w, &s3, &c3);
        sv.x = f2bf(s0); sv.y = f2bf(s1); sv.z = f2bf(s2); sv.w = f2bf(s3);
        cv.x = f2bf(c0); cv.y = f2bf(c1); cv.z = f2bf(c2); cv.w = f2bf(c3);
        *reinterpret_cast<ushort4*>(&sA[buf][0][q][r][h * 4]) = sv;
        *reinterpret_cast<ushort4*>(&sA[buf][1][q][r][h * 4]) = cv;
    };

    auto compute = [&](int buf) {
        const int kq = lane >> 4;   // k-chunk for this lane
        const int lr = lane & 15;
        bf16x8 aS[2], aC[2];
#pragma unroll
        for (int mi = 0; mi < 2; ++mi) {
            aS[mi] = *reinterpret_cast<const bf16x8*>(&sA[buf][0][kq][wm * 32 + mi * 16 + lr][0]);
            aC[mi] = *reinterpret_cast<const bf16x8*>(&sA[buf][1][kq][wm * 32 + mi * 16 + lr][0]);
        }
        __builtin_amdgcn_s_setprio(1);
#pragma unroll
        for (int ni = 0; ni < 8; ++ni) {
            bf16x8 bF = *reinterpret_cast<const bf16x8*>(&sB[buf][kq][wn * 128 + ni * 16 + lr][0]);
#pragma unroll
            for (int mi = 0; mi < 2; ++mi) {
                accS[mi][ni] = __builtin_amdgcn_mfma_f32_16x16x32_bf16(aS[mi], bF, accS[mi][ni], 0, 0, 0);
                accC[mi][ni] = __builtin_amdgcn_mfma_f32_16x16x32_bf16(aC[mi], bF, accC[mi][ni], 0, 0, 0);
            }
        }
        __builtin_amdgcn_s_setprio(0);
    };

    // ---- prologue: stage tile 0 (latency exposed once) ----
    {
        float4 v0 = a_load(0);
        b_issue(0, 0);
        a_finish(0, v0);
    }
    __syncthreads();

    int cur = 0;
    for (int kt = 0; kt < NKT; ++kt) {
        const bool more = (kt + 1 < NKT);
        float4 thv{0.f, 0.f, 0.f, 0.f};
        if (more) {
            thv = a_load(kt + 1);      // issue early: lands during compute
            b_issue(cur ^ 1, kt + 1);  // gload_lds in flight across compute
        }
        compute(cur);                  // no vmcnt dependence
        if (more) {
            a_finish(cur ^ 1, thv);    // vmcnt wait here: loads long landed
        }
        __syncthreads();
        cur ^= 1;
    }

    // ---- epilogue: fused elementwise ----
#pragma unroll
    for (int mi = 0; mi < 2; ++mi) {
#pragma unroll
        for (int ni = 0; ni < 8; ++ni) {
            const int colg = col0 + wn * 128 + ni * 16 + (lane & 15);
            const float om = omega[colg];
#pragma unroll
            for (int v = 0; v < 4; ++v) {
                const int rowg = row0 + wm * 32 + mi * 16 + (lane >> 4) * 4 + v;
                const size_t idx = (size_t)rowg * N_DIM + colg;
                const float th = theta[idx];
                float sn, cn;
                __sincosf(th, &sn, &cn);
                const float coup = cn * accS[mi][ni][v] - sn * accC[mi][ni][v];
                out[idx] = th + (om + coup) * DT_C + noise[idx] * NS_SCALE;
            }
        }
    }
}

extern "C" void kernel_launch(void* const* d_in, const int* in_sizes, int n_in,
                              void* d_out, int out_size, void* d_ws, size_t ws_size,
                              hipStream_t stream) {
    const float* theta = (const float*)d_in[0];
    const float* noise = (const float*)d_in[1];
    const float* omega = (const float*)d_in[2];
    const float* K     = (const float*)d_in[3];
    float* out = (float*)d_out;

    unsigned short* Kbf = (unsigned short*)d_ws;   // 2 MB

    // K -> bf16
    k_convK<<<(N_DIM * N_DIM) / (256 * 4), 256, 0, stream>>>(K, Kbf);

    // fused GEMM + epilogue
    const int grid = (B_DIM / BM) * (N_DIM / BN);  // 2048
    k_fused<<<grid, THREADS, 0, stream>>>(theta, noise, omega, Kbf, out);
}

// Round 3
// 585.011 us; speedup vs baseline: 1.3001x; 1.3001x over previous
//
#include <hip/hip_runtime.h>
#include <hip/hip_bf16.h>
#include <math.h>

#define B_DIM 65536
#define N_DIM 1024
#define BM 64
#define BN 256
#define BK 32
#define NKT (N_DIM / BK)
#define THREADS 512
#define DT_C 0.01f
#define NS_SCALE 0.01f   // NOISE_STD * sqrt(DT) = 0.1 * 0.1

typedef __attribute__((ext_vector_type(8))) short bf16x8;
typedef __attribute__((ext_vector_type(4))) float f32x4;

__device__ __forceinline__ unsigned short f2bf(float f) {
    union { float f; unsigned int u; } a;
    a.f = f;
    unsigned int r = a.u + 0x7fffu + ((a.u >> 16) & 1u);
    return (unsigned short)(r >> 16);
}

__device__ __forceinline__ void gload_lds16(const void* g, void* l) {
    __builtin_amdgcn_global_load_lds(
        (const __attribute__((address_space(1))) void*)g,
        (__attribute__((address_space(3))) void*)l, 16, 0, 0);
}

// K (fp32, row-major N x N) -> bf16
__global__ void k_convK(const float* __restrict__ K, unsigned short* __restrict__ Kbf) {
    int i = blockIdx.x * blockDim.x + threadIdx.x;
    float4 v = reinterpret_cast<const float4*>(K)[i];
    ushort4 o;
    o.x = f2bf(v.x); o.y = f2bf(v.y); o.z = f2bf(v.z); o.w = f2bf(v.w);
    reinterpret_cast<ushort4*>(Kbf)[i] = o;
}

// Fused: Ks = sin(theta) @ K^T, Kc = cos(theta) @ K^T (bf16 MFMA),
// out = theta + (omega + cos*Ks - sin*Kc)*DT + noise*NS_SCALE
__global__ __launch_bounds__(THREADS, 4)
void k_fused(const float* __restrict__ theta,
             const float* __restrict__ noise,
             const float* __restrict__ omega,
             const unsigned short* __restrict__ Kbf,
             float* __restrict__ out) {
    // LDS: k-chunk-major 16B granules. 48 KB total -> 2-3 blocks/CU resident.
    __shared__ unsigned short sA[2][2][4][BM][8];     // 16 KB
    __shared__ unsigned short sB[2][4][BN][8];        // 32 KB

    const int tid  = threadIdx.x;
    const int lane = tid & 63;
    const int w    = tid >> 6;       // wave 0..7
    const int wm   = w >> 2;         // 0..1  (32 rows each)
    const int wn   = w & 3;          // 0..3  (64 cols each)

    // XCD-aware swizzle: group the 4 column-tiles of a row-panel on one XCD
    const int nwg     = gridDim.x;         // 4096, divisible by 8
    const int cpx     = nwg >> 3;
    const int logical = (blockIdx.x & 7) * cpx + (blockIdx.x >> 3);
    const int mt      = logical >> 2;      // 0..1023
    const int nt      = logical & 3;       // 0..3
    const int row0    = mt * BM;
    const int col0    = nt * BN;

    // staging decomposition for A: thread -> (q, r, h)
    const int q = tid >> 7;          // k-chunk 0..3
    const int r = (tid >> 1) & 63;   // row 0..63
    const int h = tid & 1;           // half 0..1 (4 elems)

    // staging decomposition for B: wave -> (it pair, row block)
    const int rb  = (w & 3) * 64;    // row base within B tile
    const int it0 = (w >> 2) * 2;    // k-granule base

    f32x4 accS[2][4], accC[2][4];
#pragma unroll
    for (int mi = 0; mi < 2; ++mi)
#pragma unroll
        for (int ni = 0; ni < 4; ++ni) {
            accS[mi][ni] = (f32x4){0.f, 0.f, 0.f, 0.f};
            accC[mi][ni] = (f32x4){0.f, 0.f, 0.f, 0.f};
        }

    auto stage = [&](int buf, int kt) {
        // ---- B first: K tile via global_load_lds (flies during sincos) ----
#pragma unroll
        for (int j = 0; j < 2; ++j) {
            const int it = it0 + j;
            const unsigned short* src =
                Kbf + (size_t)(col0 + rb + lane) * N_DIM + kt * BK + it * 8;
            unsigned short* dst = &sB[buf][it][rb][0];
            gload_lds16(src, dst);
        }
        // ---- A: load theta, sincos, pack bf16, ds_write ----
        const float* gp = theta + (size_t)(row0 + r) * N_DIM + kt * BK + q * 8 + h * 4;
        float4 v = *reinterpret_cast<const float4*>(gp);
        ushort4 sv, cv;
        {
            float s0, c0, s1, c1, s2, c2, s3, c3;
            __sincosf(v.x, &s0, &c0);
            __sincosf(v.y, &s1, &c1);
            __sincosf(v.z, &s2, &c2);
            __sincosf(v.w, &s3, &c3);
            sv.x = f2bf(s0); sv.y = f2bf(s1); sv.z = f2bf(s2); sv.w = f2bf(s3);
            cv.x = f2bf(c0); cv.y = f2bf(c1); cv.z = f2bf(c2); cv.w = f2bf(c3);
        }
        *reinterpret_cast<ushort4*>(&sA[buf][0][q][r][h * 4]) = sv;
        *reinterpret_cast<ushort4*>(&sA[buf][1][q][r][h * 4]) = cv;
    };

    auto compute = [&](int buf) {
        const int kq = lane >> 4;   // k-chunk for this lane
        const int lr = lane & 15;
        bf16x8 aS[2], aC[2];
#pragma unroll
        for (int mi = 0; mi < 2; ++mi) {
            aS[mi] = *reinterpret_cast<const bf16x8*>(&sA[buf][0][kq][wm * 32 + mi * 16 + lr][0]);
            aC[mi] = *reinterpret_cast<const bf16x8*>(&sA[buf][1][kq][wm * 32 + mi * 16 + lr][0]);
        }
#pragma unroll
        for (int ni = 0; ni < 4; ++ni) {
            bf16x8 bF = *reinterpret_cast<const bf16x8*>(&sB[buf][kq][wn * 64 + ni * 16 + lr][0]);
#pragma unroll
            for (int mi = 0; mi < 2; ++mi) {
                accS[mi][ni] = __builtin_amdgcn_mfma_f32_16x16x32_bf16(aS[mi], bF, accS[mi][ni], 0, 0, 0);
                accC[mi][ni] = __builtin_amdgcn_mfma_f32_16x16x32_bf16(aC[mi], bF, accC[mi][ni], 0, 0, 0);
            }
        }
    };

    stage(0, 0);
    __syncthreads();
    int cur = 0;
    for (int kt = 0; kt < NKT; ++kt) {
        if (kt + 1 < NKT) stage(cur ^ 1, kt + 1);
        compute(cur);
        __syncthreads();
        cur ^= 1;
    }

    // ---- epilogue: fused elementwise ----
#pragma unroll
    for (int mi = 0; mi < 2; ++mi) {
#pragma unroll
        for (int ni = 0; ni < 4; ++ni) {
            const int colg = col0 + wn * 64 + ni * 16 + (lane & 15);
            const float om = omega[colg];
#pragma unroll
            for (int v = 0; v < 4; ++v) {
                const int rowg = row0 + wm * 32 + mi * 16 + (lane >> 4) * 4 + v;
                const size_t idx = (size_t)rowg * N_DIM + colg;
                const float th = theta[idx];
                float sn, cn;
                __sincosf(th, &sn, &cn);
                const float coup = cn * accS[mi][ni][v] - sn * accC[mi][ni][v];
                out[idx] = th + (om + coup) * DT_C + noise[idx] * NS_SCALE;
            }
        }
    }
}

extern "C" void kernel_launch(void* const* d_in, const int* in_sizes, int n_in,
                              void* d_out, int out_size, void* d_ws, size_t ws_size,
                              hipStream_t stream) {
    const float* theta = (const float*)d_in[0];
    const float* noise = (const float*)d_in[1];
    const float* omega = (const float*)d_in[2];
    const float* K     = (const float*)d_in[3];
    float* out = (float*)d_out;

    unsigned short* Kbf = (unsigned short*)d_ws;   // 2 MB

    // K -> bf16
    k_convK<<<(N_DIM * N_DIM) / (256 * 4), 256, 0, stream>>>(K, Kbf);

    // fused GEMM + epilogue
    const int grid = (B_DIM / BM) * (N_DIM / BN);  // 4096
    k_fused<<<grid, THREADS, 0, stream>>>(theta, noise, omega, Kbf, out);
}